// Round 11
// baseline (121.485 us; speedup 1.0000x reference)
//
#include <hip/hip_runtime.h>
#include <hip/hip_bf16.h>
#include <math.h>

#define N_Q   512
#define M_ALL 2048
#define CHN   256
#define TOPK  6
#define INV_C (1.0f / 256.0f)

// ws layout (float offsets): [64..576) per-n loss, [4096..) logits [N][M]
#define WS_LOSS  64
#define WS_LOGIT 4096

typedef __bf16 bf16x8 __attribute__((ext_vector_type(8)));
typedef float  f32x4  __attribute__((ext_vector_type(4)));

static __device__ __forceinline__ unsigned short bfbits(float x) {
    __bf16 h = (__bf16)x;
    unsigned short u;
    __builtin_memcpy(&u, &h, 2);
    return u;
}

// =============== kernel 1: fused bias + MFMA-bf16 GEMM (approx logits) ===============
#define BM 64
#define BN 32
#define LDK 264   // 256 + 8 bf16 pad

__global__ __launch_bounds__(256) void gcn_gemm(
    const float* __restrict__ micro_all,  // A [M, C]
    const float* __restrict__ micro,      // B [N, C]
    const float* __restrict__ fc_w,
    float* __restrict__ logits)           // [N_Q][M_ALL]
{
    __shared__ unsigned short sA[BM][LDK];  // bf16 bits of w~*micro_all, [m][k]
    __shared__ unsigned short sB[BN][LDK];  // bf16 bits of micro,        [n][k]
    __shared__ float s_bias[BM];

    const int t    = threadIdx.x;
    const int w    = t >> 6;
    const int l15  = t & 15;
    const int quad = (t >> 4) & 3;
    const int m0   = blockIdx.x * BM;
    const int n0   = blockIdx.y * BN;

    const int rg = t >> 4;          // row-group 0..15
    const int c0 = (t & 15) * 4;    // channel base

    float4 wv[4];
    #pragma unroll
    for (int cc = 0; cc < 4; ++cc) {
        float4 x = *(const float4*)(fc_w + c0 + cc * 64);
        x.x -= INV_C; x.y -= INV_C; x.z -= INV_C; x.w -= INV_C;
        wv[cc] = x;
    }

    #pragma unroll
    for (int i = 0; i < 4; ++i) {
        const int r = i * 16 + rg;
        const float* rp = micro_all + (size_t)(m0 + r) * CHN;
        float p = 0.0f;
        #pragma unroll
        for (int cc = 0; cc < 4; ++cc) {
            const float4 v = *(const float4*)(rp + c0 + cc * 64);
            const float sx = v.x * wv[cc].x;
            const float sy = v.y * wv[cc].y;
            const float sz = v.z * wv[cc].z;
            const float sw = v.w * wv[cc].w;
            ushort4 pk;
            pk.x = bfbits(sx); pk.y = bfbits(sy); pk.z = bfbits(sz); pk.w = bfbits(sw);
            *(ushort4*)&sA[r][c0 + cc * 64] = pk;
            p += v.x * sx + v.y * sy + v.z * sz + v.w * sw;
        }
        #pragma unroll
        for (int mask = 8; mask >= 1; mask >>= 1)
            p += __shfl_xor(p, mask, 64);
        if ((t & 15) == 0) s_bias[r] = p;
    }

    #pragma unroll
    for (int i = 0; i < 2; ++i) {
        const int r = i * 16 + rg;
        const float* rp = micro + (size_t)(n0 + r) * CHN;
        #pragma unroll
        for (int cc = 0; cc < 4; ++cc) {
            const float4 v = *(const float4*)(rp + c0 + cc * 64);
            ushort4 pk;
            pk.x = bfbits(v.x); pk.y = bfbits(v.y); pk.z = bfbits(v.z); pk.w = bfbits(v.w);
            *(ushort4*)&sB[r][c0 + cc * 64] = pk;
        }
    }
    __syncthreads();

    const int nt    = w & 1;
    const int mtp   = w >> 1;
    const int rowB  = nt * 16 + l15;
    const int rowA0 = mtp * 32 + l15;
    const int rowA1 = mtp * 32 + 16 + l15;

    f32x4 acc0 = {0.f, 0.f, 0.f, 0.f};
    f32x4 acc1 = {0.f, 0.f, 0.f, 0.f};
    #pragma unroll
    for (int ks = 0; ks < 8; ++ks) {
        const int k0 = ks * 32 + quad * 8;
        const bf16x8 a  = *(const bf16x8*)&sB[rowB][k0];
        const bf16x8 b0 = *(const bf16x8*)&sA[rowA0][k0];
        const bf16x8 b1 = *(const bf16x8*)&sA[rowA1][k0];
        acc0 = __builtin_amdgcn_mfma_f32_16x16x32_bf16(a, b0, acc0, 0, 0, 0);
        acc1 = __builtin_amdgcn_mfma_f32_16x16x32_bf16(a, b1, acc1, 0, 0, 0);
    }

    const float bias0 = s_bias[mtp * 32 + l15];
    const float bias1 = s_bias[mtp * 32 + 16 + l15];
    #pragma unroll
    for (int reg = 0; reg < 4; ++reg) {
        const int n = n0 + nt * 16 + quad * 4 + reg;
        logits[(size_t)n * M_ALL + m0 + mtp * 32 + l15]      = bias0 - 2.f * acc0[reg];
        logits[(size_t)n * M_ALL + m0 + mtp * 32 + 16 + l15] = bias1 - 2.f * acc1[reg];
    }
}

// =============== kernel 2: candidate top-k + exact refine + epilogue ===============
#define BLOCK 256
#define WAVES (BLOCK / 64)
#define MPT   (M_ALL / BLOCK)
#define WTOP  8
#define NCAND (WAVES * WTOP)
#define NREF  10

__global__ __launch_bounds__(BLOCK) void gcn_topk(
    const float* __restrict__ logits,
    const float* __restrict__ micro,
    const float* __restrict__ label,
    const float* __restrict__ micro_all,
    const float* __restrict__ label_all,
    const float* __restrict__ fc_w,
    float* __restrict__ out,
    float* __restrict__ loss_arr)
{
    __shared__ float s_cv[NCAND];
    __shared__ int   s_ci[NCAND];
    __shared__ float s_ex[NREF];

    const int n    = blockIdx.x;
    const int t    = threadIdx.x;
    const int wave = t >> 6;
    const int lane = t & 63;

    float4 b4 = *(const float4*)(micro + (size_t)n * CHN + lane * 4);
    float4 w4 = *(const float4*)(fc_w + lane * 4);
    w4.x -= INV_C; w4.y -= INV_C; w4.z -= INV_C; w4.w -= INV_C;

    float logit[MPT];
    #pragma unroll
    for (int j = 0; j < MPT; ++j)
        logit[j] = logits[(size_t)n * M_ALL + t + j * BLOCK];

    unsigned taken = 0u;
    #pragma unroll
    for (int k = 0; k < WTOP; ++k) {
        float best  = -INFINITY;
        int   bestj = -1;
        #pragma unroll
        for (int j = 0; j < MPT; ++j) {
            bool avail = ((taken >> j) & 1u) == 0u;
            if (avail && logit[j] > best) { best = logit[j]; bestj = j; }
        }
        float v  = best;
        int   mi = (bestj < 0) ? -1 : (t + bestj * BLOCK);
        #pragma unroll
        for (int mask = 32; mask > 0; mask >>= 1) {
            float ov = __shfl_xor(v,  mask, 64);
            int   om = __shfl_xor(mi, mask, 64);
            if (ov > v) { v = ov; mi = om; }
        }
        if (lane == 0) {
            s_cv[wave * WTOP + k] = v;
            s_ci[wave * WTOP + k] = mi;
        }
        if (mi >= 0 && t == (mi & (BLOCK - 1))) taken |= 1u << (mi >> 8);
    }
    __syncthreads();

    float tv[NREF];
    int   ti[NREF];
    unsigned ctk = 0u;
    #pragma unroll
    for (int k = 0; k < NREF; ++k) {
        float best = -INFINITY;
        int   bi   = 0;
        #pragma unroll
        for (int c = 0; c < NCAND; ++c) {
            bool avail = ((ctk >> c) & 1u) == 0u;
            float cv = s_cv[c];
            if (avail && cv > best) { best = cv; bi = c; }
        }
        tv[k] = best;
        ti[k] = s_ci[bi];
        ctk |= 1u << bi;
    }

    for (int c = wave; c < NREF; c += WAVES) {
        const int m = ti[c];
        const float4 a = *(const float4*)(micro_all + (size_t)m * CHN + lane * 4);
        const float dx = a.x - b4.x;
        const float dy = a.y - b4.y;
        const float dz = a.z - b4.z;
        const float dw = a.w - b4.w;
        float acc = dx * dx * w4.x + dy * dy * w4.y + dz * dz * w4.z + dw * dw * w4.w;
        #pragma unroll
        for (int mask = 32; mask >= 1; mask >>= 1)
            acc += __shfl_xor(acc, mask, 64);
        if (lane == 0) s_ex[c] = acc;
    }
    __syncthreads();

    float top_val[TOPK];
    int   top_idx[TOPK];
    unsigned rtk = 0u;
    #pragma unroll
    for (int k = 0; k < TOPK; ++k) {
        float best = -INFINITY;
        int   bi   = 0;
        #pragma unroll
        for (int c = 0; c < NREF; ++c) {
            bool avail = ((rtk >> c) & 1u) == 0u;
            float cv = s_ex[c];
            if (avail && cv > best) { best = cv; bi = c; }
        }
        top_val[k] = best;
        top_idx[k] = ti[bi];
        rtk |= 1u << bi;
    }

    const float mx = top_val[0];
    float e[TOPK];
    float esum = 0.0f;
    #pragma unroll
    for (int k = 0; k < TOPK; ++k) { e[k] = __expf(top_val[k] - mx); esum += e[k]; }
    const float inv = 1.0f / esum;

    float outv = micro[(size_t)n * CHN + t];
    #pragma unroll
    for (int k = 0; k < TOPK; ++k)
        outv += (e[k] * inv) * micro_all[(size_t)top_idx[k] * CHN + t];
    out[n * CHN + t] = outv;

    if (t == 0) {
        const float lab = label[n];
        float l = 0.0f;
        #pragma unroll
        for (int k = 0; k < TOPK; ++k)
            l += (e[k] * inv) * fabsf(label_all[top_idx[k]] - lab);
        loss_arr[n] = l;
    }
}

// =============== kernel 3: reduce 512 per-n losses ===============
__global__ __launch_bounds__(256) void gcn_finalize(
    const float* __restrict__ loss_arr,
    float* __restrict__ out)
{
    __shared__ float red[4];
    const int t = threadIdx.x;
    float v = loss_arr[t] + loss_arr[t + 256];
    #pragma unroll
    for (int mask = 32; mask >= 1; mask >>= 1)
        v += __shfl_xor(v, mask, 64);
    if ((t & 63) == 0) red[t >> 6] = v;
    __syncthreads();
    if (t == 0)
        out[N_Q * CHN] = 1e-4f + (red[0] + red[1] + red[2] + red[3]) / (float)N_Q;
}

extern "C" void kernel_launch(void* const* d_in, const int* in_sizes, int n_in,
                              void* d_out, int out_size, void* d_ws, size_t ws_size,
                              hipStream_t stream) {
    const float* micro     = (const float*)d_in[0];
    const float* label     = (const float*)d_in[1];
    const float* micro_all = (const float*)d_in[2];
    const float* label_all = (const float*)d_in[3];
    const float* fc_w      = (const float*)d_in[4];
    float* out    = (float*)d_out;
    float* ws     = (float*)d_ws;
    float* loss   = ws + WS_LOSS;
    float* logits = ws + WS_LOGIT;

    // MEASUREMENT ROUND: gemm x8 (idempotent, no atomics) to pin t_gemm:
    //   g = (total11 - 87.45) / 7 ;  T+fin = 30.9 - g
    for (int rep = 0; rep < 8; ++rep) {
        gcn_gemm<<<dim3(M_ALL / BM, N_Q / BN), 256, 0, stream>>>(
            micro_all, micro, fc_w, logits);
    }
    gcn_topk<<<N_Q, BLOCK, 0, stream>>>(logits, micro, label, micro_all,
                                        label_all, fc_w, out, loss);
    gcn_finalize<<<1, 256, 0, stream>>>(loss, out);
}

// Round 12
// 78.356 us; speedup vs baseline: 1.5504x; 1.5504x over previous
//
#include <hip/hip_runtime.h>
#include <hip/hip_bf16.h>
#include <math.h>

#define N_Q   512
#define M_ALL 2048
#define CHN   256
#define TOPK  6
#define INV_C (1.0f / 256.0f)

// ws layout (float offsets): [64..576) per-n loss, [4096..) logits [N][M]
#define WS_LOSS  64
#define WS_LOGIT 4096

typedef __bf16 bf16x8 __attribute__((ext_vector_type(8)));
typedef float  f32x4  __attribute__((ext_vector_type(4)));

static __device__ __forceinline__ unsigned short bfbits(float x) {
    __bf16 h = (__bf16)x;
    unsigned short u;
    __builtin_memcpy(&u, &h, 2);
    return u;
}

// =============== kernel 1: fused bias + MFMA-bf16 GEMM (approx logits) ===============
#define BM 64
#define BN 32
#define LDK 264   // 256 + 8 bf16 pad

__global__ __launch_bounds__(256) void gcn_gemm(
    const float* __restrict__ micro_all,  // A [M, C]
    const float* __restrict__ micro,      // B [N, C]
    const float* __restrict__ fc_w,
    float* __restrict__ logits)           // [N_Q][M_ALL]
{
    __shared__ unsigned short sA[BM][LDK];
    __shared__ unsigned short sB[BN][LDK];
    __shared__ float s_bias[BM];

    const int t    = threadIdx.x;
    const int w    = t >> 6;
    const int l15  = t & 15;
    const int quad = (t >> 4) & 3;
    const int m0   = blockIdx.x * BM;
    const int n0   = blockIdx.y * BN;

    const int rg = t >> 4;
    const int c0 = (t & 15) * 4;

    float4 wv[4];
    #pragma unroll
    for (int cc = 0; cc < 4; ++cc) {
        float4 x = *(const float4*)(fc_w + c0 + cc * 64);
        x.x -= INV_C; x.y -= INV_C; x.z -= INV_C; x.w -= INV_C;
        wv[cc] = x;
    }

    #pragma unroll
    for (int i = 0; i < 4; ++i) {
        const int r = i * 16 + rg;
        const float* rp = micro_all + (size_t)(m0 + r) * CHN;
        float p = 0.0f;
        #pragma unroll
        for (int cc = 0; cc < 4; ++cc) {
            const float4 v = *(const float4*)(rp + c0 + cc * 64);
            const float sx = v.x * wv[cc].x;
            const float sy = v.y * wv[cc].y;
            const float sz = v.z * wv[cc].z;
            const float sw = v.w * wv[cc].w;
            ushort4 pk;
            pk.x = bfbits(sx); pk.y = bfbits(sy); pk.z = bfbits(sz); pk.w = bfbits(sw);
            *(ushort4*)&sA[r][c0 + cc * 64] = pk;
            p += v.x * sx + v.y * sy + v.z * sz + v.w * sw;
        }
        #pragma unroll
        for (int mask = 8; mask >= 1; mask >>= 1)
            p += __shfl_xor(p, mask, 64);
        if ((t & 15) == 0) s_bias[r] = p;
    }

    #pragma unroll
    for (int i = 0; i < 2; ++i) {
        const int r = i * 16 + rg;
        const float* rp = micro + (size_t)(n0 + r) * CHN;
        #pragma unroll
        for (int cc = 0; cc < 4; ++cc) {
            const float4 v = *(const float4*)(rp + c0 + cc * 64);
            ushort4 pk;
            pk.x = bfbits(v.x); pk.y = bfbits(v.y); pk.z = bfbits(v.z); pk.w = bfbits(v.w);
            *(ushort4*)&sB[r][c0 + cc * 64] = pk;
        }
    }
    __syncthreads();

    const int nt    = w & 1;
    const int mtp   = w >> 1;
    const int rowB  = nt * 16 + l15;
    const int rowA0 = mtp * 32 + l15;
    const int rowA1 = mtp * 32 + 16 + l15;

    f32x4 acc0 = {0.f, 0.f, 0.f, 0.f};
    f32x4 acc1 = {0.f, 0.f, 0.f, 0.f};
    #pragma unroll
    for (int ks = 0; ks < 8; ++ks) {
        const int k0 = ks * 32 + quad * 8;
        const bf16x8 a  = *(const bf16x8*)&sB[rowB][k0];
        const bf16x8 b0 = *(const bf16x8*)&sA[rowA0][k0];
        const bf16x8 b1 = *(const bf16x8*)&sA[rowA1][k0];
        acc0 = __builtin_amdgcn_mfma_f32_16x16x32_bf16(a, b0, acc0, 0, 0, 0);
        acc1 = __builtin_amdgcn_mfma_f32_16x16x32_bf16(a, b1, acc1, 0, 0, 0);
    }

    const float bias0 = s_bias[mtp * 32 + l15];
    const float bias1 = s_bias[mtp * 32 + 16 + l15];
    #pragma unroll
    for (int reg = 0; reg < 4; ++reg) {
        const int n = n0 + nt * 16 + quad * 4 + reg;
        logits[(size_t)n * M_ALL + m0 + mtp * 32 + l15]      = bias0 - 2.f * acc0[reg];
        logits[(size_t)n * M_ALL + m0 + mtp * 32 + 16 + l15] = bias1 - 2.f * acc1[reg];
    }
}

// =============== kernel 2: packed-key top-k + exact refine + epilogue ===============
#define BLOCK 256
#define WAVES (BLOCK / 64)
#define MPT   (M_ALL / BLOCK)
#define WTOP  8                   // per-wave exhaustive top-8 (packed keys)
#define NCAND (WAVES * WTOP)      // 32
#define NREF  10                  // exact-refined candidates

// sortable u32 key with 11-bit m-index embedded in the low (dropped) mantissa bits
static __device__ __forceinline__ unsigned key_of(float f, int m) {
    unsigned u = __float_as_uint(f);
    u = (u & 0x80000000u) ? ~u : (u | 0x80000000u);
    return (u & 0xFFFFF800u) | (unsigned)m;
}

__global__ __launch_bounds__(BLOCK) void gcn_topk(
    const float* __restrict__ logits,
    const float* __restrict__ micro,
    const float* __restrict__ label,
    const float* __restrict__ micro_all,
    const float* __restrict__ label_all,
    const float* __restrict__ fc_w,
    float* __restrict__ out,
    float* __restrict__ loss_arr)
{
    __shared__ unsigned s_keys[NCAND];
    __shared__ unsigned s_top[NREF];
    __shared__ float    s_ex[NREF];

    const int n    = blockIdx.x;
    const int t    = threadIdx.x;
    const int wave = t >> 6;
    const int lane = t & 63;

    // per-lane channel slice for the exact recompute (independent of logits)
    const float4 b4 = *(const float4*)(micro + (size_t)n * CHN + lane * 4);
    float4 w4 = *(const float4*)(fc_w + lane * 4);
    w4.x -= INV_C; w4.y -= INV_C; w4.z -= INV_C; w4.w -= INV_C;

    // load + pack 8 logits (m = t + j*256 fits 11 bits)
    unsigned k8[MPT];
    #pragma unroll
    for (int j = 0; j < MPT; ++j) {
        const int m = t + j * BLOCK;
        k8[j] = key_of(logits[(size_t)n * M_ALL + m], m);
    }

    // ---- per-wave exhaustive top-8 via packed umax butterflies ----
    #pragma unroll
    for (int k = 0; k < WTOP; ++k) {
        unsigned best = k8[0];
        #pragma unroll
        for (int j = 1; j < MPT; ++j) best = (k8[j] > best) ? k8[j] : best;
        #pragma unroll
        for (int mask = 32; mask > 0; mask >>= 1) {
            const unsigned ov = __shfl_xor(best, mask, 64);
            best = (ov > best) ? ov : best;
        }
        if (lane == 0) s_keys[wave * WTOP + k] = best;
        #pragma unroll
        for (int j = 0; j < MPT; ++j)
            k8[j] = (k8[j] == best) ? 0u : k8[j];
    }
    __syncthreads();

    // ---- top-10 of the 32 candidates: 32-lane bitonic sort (descending) ----
    {
        unsigned v = s_keys[lane & 31];
        #pragma unroll
        for (int k = 2; k <= 32; k <<= 1) {
            #pragma unroll
            for (int j = k >> 1; j >= 1; j >>= 1) {
                const unsigned pv = __shfl_xor(v, j, 64);
                const unsigned mx = (v > pv) ? v : pv;
                const unsigned mn = (v > pv) ? pv : v;
                const bool up    = ((lane & k) == 0);
                const bool lower = ((lane & j) == 0);
                v = (up == lower) ? mx : mn;   // descending in "up" blocks
            }
        }
        if (wave == 0 && lane < NREF) s_top[lane] = v;  // lanes 0..9 descending
    }
    __syncthreads();

    // ---- exact fp32 recompute of the 10 candidates ----
    for (int c = wave; c < NREF; c += WAVES) {
        const int m = (int)(s_top[c] & 0x7FFu);
        const float4 a = *(const float4*)(micro_all + (size_t)m * CHN + lane * 4);
        const float dx = a.x - b4.x;
        const float dy = a.y - b4.y;
        const float dz = a.z - b4.z;
        const float dw = a.w - b4.w;
        float acc = dx * dx * w4.x + dy * dy * w4.y + dz * dz * w4.z + dw * dw * w4.w;
        #pragma unroll
        for (int mask = 32; mask >= 1; mask >>= 1)
            acc += __shfl_xor(acc, mask, 64);
        if (lane == 0) s_ex[c] = acc;
    }
    __syncthreads();

    // ---- exact top-6 of 10 (fp32, index-tracked, every thread identical) ----
    float top_val[TOPK];
    int   top_idx[TOPK];
    unsigned rtk = 0u;
    #pragma unroll
    for (int k = 0; k < TOPK; ++k) {
        float best = -INFINITY;
        int   bi   = 0;
        #pragma unroll
        for (int c = 0; c < NREF; ++c) {
            const bool avail = ((rtk >> c) & 1u) == 0u;
            const float cv = s_ex[c];
            if (avail && cv > best) { best = cv; bi = c; }
        }
        top_val[k] = best;
        top_idx[k] = (int)(s_top[bi] & 0x7FFu);
        rtk |= 1u << bi;
    }

    // ---- softmax over exact top-6 ----
    const float mx = top_val[0];
    float e[TOPK];
    float esum = 0.0f;
    #pragma unroll
    for (int k = 0; k < TOPK; ++k) { e[k] = __expf(top_val[k] - mx); esum += e[k]; }
    const float inv = 1.0f / esum;

    float outv = micro[(size_t)n * CHN + t];
    #pragma unroll
    for (int k = 0; k < TOPK; ++k)
        outv += (e[k] * inv) * micro_all[(size_t)top_idx[k] * CHN + t];
    out[n * CHN + t] = outv;

    if (t == 0) {
        const float lab = label[n];
        float l = 0.0f;
        #pragma unroll
        for (int k = 0; k < TOPK; ++k)
            l += (e[k] * inv) * fabsf(label_all[top_idx[k]] - lab);
        loss_arr[n] = l;
    }
}

// =============== kernel 3: reduce 512 per-n losses ===============
__global__ __launch_bounds__(256) void gcn_finalize(
    const float* __restrict__ loss_arr,
    float* __restrict__ out)
{
    __shared__ float red[4];
    const int t = threadIdx.x;
    float v = loss_arr[t] + loss_arr[t + 256];
    #pragma unroll
    for (int mask = 32; mask >= 1; mask >>= 1)
        v += __shfl_xor(v, mask, 64);
    if ((t & 63) == 0) red[t >> 6] = v;
    __syncthreads();
    if (t == 0)
        out[N_Q * CHN] = 1e-4f + (red[0] + red[1] + red[2] + red[3]) / (float)N_Q;
}

extern "C" void kernel_launch(void* const* d_in, const int* in_sizes, int n_in,
                              void* d_out, int out_size, void* d_ws, size_t ws_size,
                              hipStream_t stream) {
    const float* micro     = (const float*)d_in[0];
    const float* label     = (const float*)d_in[1];
    const float* micro_all = (const float*)d_in[2];
    const float* label_all = (const float*)d_in[3];
    const float* fc_w      = (const float*)d_in[4];
    float* out    = (float*)d_out;
    float* ws     = (float*)d_ws;
    float* loss   = ws + WS_LOSS;
    float* logits = ws + WS_LOGIT;

    gcn_gemm<<<dim3(M_ALL / BM, N_Q / BN), 256, 0, stream>>>(
        micro_all, micro, fc_w, logits);
    gcn_topk<<<N_Q, BLOCK, 0, stream>>>(logits, micro, label, micro_all,
                                        label_all, fc_w, out, loss);
    gcn_finalize<<<1, 256, 0, stream>>>(loss, out);
}